// Round 1
// baseline (627.669 us; speedup 1.0000x reference)
//
#include <hip/hip_runtime.h>
#include <hip/hip_bf16.h>
#include <stdint.h>

#define Tdim 4096
#define Ndim 4096
#define Kdim 4096
#define K2   4160   // 4096 + 32 (low-rank concat) + 32 (zero pad to multiple of 64)

using f32x4  = __attribute__((ext_vector_type(4))) float;
using bf16x8 = __attribute__((ext_vector_type(8))) short;

// round-to-nearest-even f32 -> bf16 bits
__device__ inline ushort f2bf(float f) {
  union { float f; unsigned u; } v; v.f = f;
  unsigned lsb = (v.u >> 16) & 1u;
  v.u += 0x7fffu + lsb;
  return (ushort)(v.u >> 16);
}

__device__ inline void async16(const void* g, void* l) {
  __builtin_amdgcn_global_load_lds(
      (const __attribute__((address_space(1))) unsigned int*)g,
      (__attribute__((address_space(3))) unsigned int*)l, 16, 0, 0);
}

// ---------------- K1: t = (x*smooth) @ proj_down  [T,32] f32 ----------------
__global__ __launch_bounds__(256) void lowrank_t_kernel(
    const float* __restrict__ x, const float* __restrict__ pd,
    const float* __restrict__ smooth, float* __restrict__ t) {
  __shared__ float spd[64 * 33];
  const int tid  = threadIdx.x;
  const int lane = tid & 63;
  const int wave = tid >> 6;
  const int token = blockIdx.x * 4 + wave;
  float acc[32];
#pragma unroll
  for (int r = 0; r < 32; ++r) acc[r] = 0.f;
  for (int kc = 0; kc < 64; ++kc) {
    const int k0 = kc * 64;
#pragma unroll
    for (int i = 0; i < 8; ++i) {
      int idx = tid + i * 256;          // 2048 elems: 64 k x 32 r
      int kk = idx >> 5, r = idx & 31;
      spd[kk * 33 + r] = pd[(size_t)(k0 + kk) * 32 + r];
    }
    __syncthreads();
    float xv = x[(size_t)token * Kdim + k0 + lane] * smooth[k0 + lane];
#pragma unroll
    for (int r = 0; r < 32; ++r) acc[r] += xv * spd[lane * 33 + r];
    __syncthreads();
  }
#pragma unroll
  for (int r = 0; r < 32; ++r) {
    float v = acc[r];
    v += __shfl_xor(v, 1);
    v += __shfl_xor(v, 2);
    v += __shfl_xor(v, 4);
    v += __shfl_xor(v, 8);
    v += __shfl_xor(v, 16);
    v += __shfl_xor(v, 32);
    acc[r] = v;
  }
  if (lane == 0) {
#pragma unroll
    for (int r = 0; r < 32; ++r) t[(size_t)token * 32 + r] = acc[r];
  }
}

// ------------- K2: quantize+dequantize activations -> A' bf16 ---------------
__global__ __launch_bounds__(256) void quant_x_kernel(
    const float* __restrict__ x, const float* __restrict__ smooth,
    ushort* __restrict__ A) {
  const int tid  = threadIdx.x;
  const int lane = tid & 63;
  const int wave = tid >> 6;
  const int gid  = blockIdx.x * 4 + wave;   // token*64 + group
  const int token = gid >> 6;
  const int g     = gid & 63;
  const int k     = g * 64 + lane;
  const float xv = x[(size_t)token * Kdim + k] * smooth[k];
  float a = fabsf(xv);
  a = fmaxf(a, __shfl_xor(a, 1));
  a = fmaxf(a, __shfl_xor(a, 2));
  a = fmaxf(a, __shfl_xor(a, 4));
  a = fmaxf(a, __shfl_xor(a, 8));
  a = fmaxf(a, __shfl_xor(a, 16));
  a = fmaxf(a, __shfl_xor(a, 32));
  const float s = fmaxf(a / 7.0f, 1e-8f);
  float q = rintf(xv / s);                  // round half to even, matches jnp.round
  q = fminf(fmaxf(q, -8.0f), 7.0f);
  A[(size_t)token * K2 + k] = f2bf(q * s);
}

// ---------------- K3a: A' tail columns = [bf16(t) | zeros] ------------------
__global__ __launch_bounds__(256) void tail_A_kernel(
    const float* __restrict__ t, ushort* __restrict__ A) {
  const int idx = blockIdx.x * 256 + threadIdx.x;  // T*64 threads
  const int token = idx >> 6, c = idx & 63;
  ushort v = 0;
  if (c < 32) v = f2bf(t[(size_t)token * 32 + c]);
  A[(size_t)token * K2 + Kdim + c] = v;
}

// ---------------- K3b: B' tail columns = [bf16(pu^T) | zeros] ---------------
__global__ __launch_bounds__(256) void tail_B_kernel(
    const float* __restrict__ pu, ushort* __restrict__ B) {
  const int idx = blockIdx.x * 256 + threadIdx.x;  // N*64 threads
  const int n = idx >> 6, c = idx & 63;
  ushort v = 0;
  if (c < 32) v = f2bf(pu[(size_t)c * Ndim + n]);  // proj_up is [32, N]
  B[(size_t)n * K2 + Kdim + c] = v;
}

// ---------------- K4: dequantize int4 weights -> B' bf16 --------------------
__global__ __launch_bounds__(256) void dequant_w_kernel(
    const int* __restrict__ qw, const float* __restrict__ wsc,
    ushort* __restrict__ B) {
  const size_t idx = ((size_t)blockIdx.x * 256 + threadIdx.x) * 4;
  const int n = (int)(idx >> 12);
  const int k = (int)(idx & 4095);
  const float s = wsc[n * 64 + (k >> 6)];
  const int4 q = *(const int4*)(qw + idx);
  ushort4 o;
  o.x = f2bf((float)q.x * s);
  o.y = f2bf((float)q.y * s);
  o.z = f2bf((float)q.z * s);
  o.w = f2bf((float)q.w * s);
  *(ushort4*)(B + (size_t)n * K2 + k) = o;
}

// ---------------- K5: C = A' @ B'^T + bias  (m97 structure) -----------------
__global__ __launch_bounds__(256) void gemm_kernel(
    const ushort* __restrict__ A, const ushort* __restrict__ B,
    const float* __restrict__ bias, float* __restrict__ C) {
  __shared__ ushort sA[128 * 32];   // 8 KB
  __shared__ ushort sB[128 * 32];   // 8 KB
  const int tid  = threadIdx.x;
  const int lane = tid & 63;
  const int wave = tid >> 6;
  const int wr = (wave >> 1) * 64;   // wave's C-row offset in tile
  const int wc = (wave & 1) * 64;    // wave's C-col offset in tile
  const int fr = lane & 15;
  const int fk = (lane >> 4) * 8;
  const size_t arow0 = (size_t)blockIdx.x * 128;
  const size_t brow0 = (size_t)blockIdx.y * 128;
  const int srow = tid >> 2;         // staging: row 0..63 (+64 for 2nd chunk)
  const int skc  = (tid & 3) * 8;    // staging: k offset (elements)

  f32x4 acc[4][4] = {};

  for (int k0 = 0; k0 < K2; k0 += 32) {
    const ushort* gA0 = A + (arow0 + srow) * K2 + k0 + skc;
    const ushort* gB0 = B + (brow0 + srow) * K2 + k0 + skc;
    async16(gA0,                    &sA[tid * 8]);
    async16(gA0 + (size_t)64 * K2,  &sA[(tid + 256) * 8]);
    async16(gB0,                    &sB[tid * 8]);
    async16(gB0 + (size_t)64 * K2,  &sB[(tid + 256) * 8]);
    __syncthreads();

    bf16x8 af[4], bfr[4];
#pragma unroll
    for (int i = 0; i < 4; ++i)
      af[i] = *(const bf16x8*)&sA[(wr + i * 16 + fr) * 32 + fk];
#pragma unroll
    for (int j = 0; j < 4; ++j)
      bfr[j] = *(const bf16x8*)&sB[(wc + j * 16 + fr) * 32 + fk];
#pragma unroll
    for (int i = 0; i < 4; ++i)
#pragma unroll
      for (int j = 0; j < 4; ++j)
        acc[i][j] = __builtin_amdgcn_mfma_f32_16x16x32_bf16(af[i], bfr[j], acc[i][j], 0, 0, 0);
    __syncthreads();
  }

  const int rq = (lane >> 4) * 4;
#pragma unroll
  for (int j = 0; j < 4; ++j) {
    const size_t col = brow0 + wc + j * 16 + fr;
    const float bv = bias[col];
#pragma unroll
    for (int i = 0; i < 4; ++i) {
      const size_t row = arow0 + wr + i * 16 + rq;
#pragma unroll
      for (int r = 0; r < 4; ++r)
        C[(row + r) * Ndim + col] = acc[i][j][r] + bv;
    }
  }
}

extern "C" void kernel_launch(void* const* d_in, const int* in_sizes, int n_in,
                              void* d_out, int out_size, void* d_ws, size_t ws_size,
                              hipStream_t stream) {
  const float* x      = (const float*)d_in[0];
  const int*   qw     = (const int*)d_in[1];
  const float* wsc    = (const float*)d_in[2];
  const float* pd     = (const float*)d_in[3];
  const float* pu     = (const float*)d_in[4];
  const float* smooth = (const float*)d_in[5];
  const float* bias   = (const float*)d_in[6];
  float* out = (float*)d_out;

  const size_t abytes = (size_t)Tdim * K2 * 2;         // 34,078,720
  ushort* A = (ushort*)d_ws;
  ushort* B = (ushort*)((char*)d_ws + abytes);
  float*  t = (float*)((char*)d_ws + 2 * abytes);      // T*32 f32

  hipLaunchKernelGGL(quant_x_kernel,   dim3(65536), dim3(256), 0, stream, x, smooth, A);
  hipLaunchKernelGGL(lowrank_t_kernel, dim3(1024),  dim3(256), 0, stream, x, pd, smooth, t);
  hipLaunchKernelGGL(tail_A_kernel,    dim3(1024),  dim3(256), 0, stream, t, A);
  hipLaunchKernelGGL(dequant_w_kernel, dim3(16384), dim3(256), 0, stream, qw, wsc, B);
  hipLaunchKernelGGL(tail_B_kernel,    dim3(1024),  dim3(256), 0, stream, pu, B);
  hipLaunchKernelGGL(gemm_kernel,      dim3(32, 32), dim3(256), 0, stream, A, B, bias, out);
}

// Round 2
// 380.992 us; speedup vs baseline: 1.6475x; 1.6475x over previous
//
#include <hip/hip_runtime.h>
#include <hip/hip_bf16.h>
#include <stdint.h>

#define Tdim 4096
#define Ndim 4096
#define Kdim 4096
#define K2   4160   // 4096 + 32 (low-rank concat) + 32 (zero pad to multiple of 64)

using f32x4  = __attribute__((ext_vector_type(4))) float;
using bf16x8 = __attribute__((ext_vector_type(8))) short;

// round-to-nearest-even f32 -> bf16 bits
__device__ inline ushort f2bf(float f) {
  union { float f; unsigned u; } v; v.f = f;
  unsigned lsb = (v.u >> 16) & 1u;
  v.u += 0x7fffu + lsb;
  return (ushort)(v.u >> 16);
}

__device__ inline void async16(const void* g, void* l) {
  __builtin_amdgcn_global_load_lds(
      (const __attribute__((address_space(1))) unsigned int*)g,
      (__attribute__((address_space(3))) unsigned int*)l, 16, 0, 0);
}

// ---------------- K0: pdT[n][k] = bf16(pd[k][n])  (32 x 4096) ---------------
__global__ __launch_bounds__(256) void prep_pdT_kernel(
    const float* __restrict__ pd, ushort* __restrict__ pdT) {
  const int idx = blockIdx.x * 256 + threadIdx.x;   // 32*4096 threads
  const int n = idx >> 12;
  const int k = idx & 4095;
  pdT[(size_t)n * Kdim + k] = f2bf(pd[(size_t)k * 32 + n]);
}

// -------- K1: partials[ksplit][T][32] = (x*smooth) @ pdT^T  (MFMA) ----------
// grid (32, 8): x = token-tile of 128, y = K-chunk of 512
__global__ __launch_bounds__(256) void lowrank_gemm_kernel(
    const float* __restrict__ x, const float* __restrict__ smooth,
    const ushort* __restrict__ pdT, float* __restrict__ partials) {
  __shared__ ushort sA[128 * 32];   // 8 KB
  const int tid  = threadIdx.x;
  const int lane = tid & 63;
  const int wave = tid >> 6;
  const int tok0 = blockIdx.x * 128;
  const int kc0  = blockIdx.y * 512;
  const int fr  = lane & 15;
  const int fkq = lane >> 4;        // 0..3
  const int fk  = fkq * 8;
  const int srow = tid >> 3;        // 0..31
  const int scol = (tid & 7) * 4;   // 0..28 step 4

  f32x4 acc[2][2] = {};

  for (int step = 0; step < 16; ++step) {
    const int k0 = kc0 + step * 32;
#pragma unroll
    for (int p = 0; p < 4; ++p) {
      const int r = srow + p * 32;
      const float4 xv = *(const float4*)&x[(size_t)(tok0 + r) * Kdim + k0 + scol];
      const float4 sm = *(const float4*)&smooth[k0 + scol];
      ushort4 o;
      o.x = f2bf(xv.x * sm.x);
      o.y = f2bf(xv.y * sm.y);
      o.z = f2bf(xv.z * sm.z);
      o.w = f2bf(xv.w * sm.w);
      *(ushort4*)&sA[r * 32 + scol] = o;
    }
    __syncthreads();
    bf16x8 af[2], bfr[2];
#pragma unroll
    for (int i = 0; i < 2; ++i)
      af[i] = *(const bf16x8*)&sA[(wave * 32 + i * 16 + fr) * 32 + fk];
#pragma unroll
    for (int j = 0; j < 2; ++j)
      bfr[j] = *(const bf16x8*)&pdT[(size_t)(j * 16 + fr) * Kdim + k0 + fk];
#pragma unroll
    for (int i = 0; i < 2; ++i)
#pragma unroll
      for (int j = 0; j < 2; ++j)
        acc[i][j] = __builtin_amdgcn_mfma_f32_16x16x32_bf16(af[i], bfr[j], acc[i][j], 0, 0, 0);
    __syncthreads();
  }

  float* P = partials + (size_t)blockIdx.y * Tdim * 32;
#pragma unroll
  for (int i = 0; i < 2; ++i) {
    const int row0 = tok0 + wave * 32 + i * 16 + fkq * 4;
#pragma unroll
    for (int j = 0; j < 2; ++j) {
      const int col = j * 16 + fr;
#pragma unroll
      for (int r = 0; r < 4; ++r)
        P[(size_t)(row0 + r) * 32 + col] = acc[i][j][r];
    }
  }
}

// ------- K2: reduce K-split partials -> bf16 into A tail cols [4096..4160) --
__global__ __launch_bounds__(256) void reduce_tail_A_kernel(
    const float* __restrict__ partials, ushort* __restrict__ A) {
  const int idx = blockIdx.x * 256 + threadIdx.x;   // T*64 threads
  const int token = idx >> 6, c = idx & 63;
  ushort v = 0;
  if (c < 32) {
    float s = 0.f;
#pragma unroll
    for (int p = 0; p < 8; ++p)
      s += partials[(size_t)p * Tdim * 32 + (size_t)token * 32 + c];
    v = f2bf(s);
  }
  A[(size_t)token * K2 + Kdim + c] = v;
}

// ------------- K3: quantize+dequantize activations -> A' bf16 ---------------
// one thread = 4 consecutive elems; group of 64 = 16 consecutive threads
__global__ __launch_bounds__(256) void quant_x_kernel(
    const float* __restrict__ x, const float* __restrict__ smooth,
    ushort* __restrict__ A) {
  const int g = blockIdx.x * 256 + threadIdx.x;     // T*1024 threads
  const int token = g >> 10;
  const int k = (g & 1023) * 4;
  const float4 xv = *(const float4*)&x[(size_t)token * Kdim + k];
  const float4 sm = *(const float4*)&smooth[k];
  const float v0 = xv.x * sm.x, v1 = xv.y * sm.y, v2 = xv.z * sm.z, v3 = xv.w * sm.w;
  float a = fmaxf(fmaxf(fabsf(v0), fabsf(v1)), fmaxf(fabsf(v2), fabsf(v3)));
  a = fmaxf(a, __shfl_xor(a, 1));
  a = fmaxf(a, __shfl_xor(a, 2));
  a = fmaxf(a, __shfl_xor(a, 4));
  a = fmaxf(a, __shfl_xor(a, 8));
  const float s = fmaxf(a / 7.0f, 1e-8f);           // exact div: must match np
  const float q0 = fminf(fmaxf(rintf(v0 / s), -8.f), 7.f);
  const float q1 = fminf(fmaxf(rintf(v1 / s), -8.f), 7.f);
  const float q2 = fminf(fmaxf(rintf(v2 / s), -8.f), 7.f);
  const float q3 = fminf(fmaxf(rintf(v3 / s), -8.f), 7.f);
  ushort4 o;
  o.x = f2bf(q0 * s);
  o.y = f2bf(q1 * s);
  o.z = f2bf(q2 * s);
  o.w = f2bf(q3 * s);
  *(ushort4*)&A[(size_t)token * K2 + k] = o;
}

// ---------------- K4: B' tail columns = [bf16(pu^T) | zeros] ----------------
__global__ __launch_bounds__(256) void tail_B_kernel(
    const float* __restrict__ pu, ushort* __restrict__ B) {
  const int idx = blockIdx.x * 256 + threadIdx.x;   // N*64 threads
  const int n = idx >> 6, c = idx & 63;
  ushort v = 0;
  if (c < 32) v = f2bf(pu[(size_t)c * Ndim + n]);   // proj_up is [32, N]
  B[(size_t)n * K2 + Kdim + c] = v;
}

// ---------------- K5: dequantize int4 weights -> B' bf16 --------------------
__global__ __launch_bounds__(256) void dequant_w_kernel(
    const int* __restrict__ qw, const float* __restrict__ wsc,
    ushort* __restrict__ B) {
  const size_t idx = ((size_t)blockIdx.x * 256 + threadIdx.x) * 8;
  const int n = (int)(idx >> 12);
  const int k = (int)(idx & 4095);
  const float s = wsc[n * 64 + (k >> 6)];           // 8 elems stay in one group
  const int4 q0 = *(const int4*)(qw + idx);
  const int4 q1 = *(const int4*)(qw + idx + 4);
  ushort4 o0, o1;
  o0.x = f2bf((float)q0.x * s);
  o0.y = f2bf((float)q0.y * s);
  o0.z = f2bf((float)q0.z * s);
  o0.w = f2bf((float)q0.w * s);
  o1.x = f2bf((float)q1.x * s);
  o1.y = f2bf((float)q1.y * s);
  o1.z = f2bf((float)q1.z * s);
  o1.w = f2bf((float)q1.w * s);
  ushort* dst = B + (size_t)n * K2 + k;
  *(ushort4*)dst = o0;
  *(ushort4*)(dst + 4) = o1;
}

// ---------------- K6: C = A' @ B'^T + bias  (m97 structure) -----------------
__global__ __launch_bounds__(256) void gemm_kernel(
    const ushort* __restrict__ A, const ushort* __restrict__ B,
    const float* __restrict__ bias, float* __restrict__ C) {
  __shared__ ushort sA[128 * 32];   // 8 KB
  __shared__ ushort sB[128 * 32];   // 8 KB
  const int tid  = threadIdx.x;
  const int lane = tid & 63;
  const int wave = tid >> 6;
  const int wr = (wave >> 1) * 64;   // wave's C-row offset in tile
  const int wc = (wave & 1) * 64;    // wave's C-col offset in tile
  const int fr = lane & 15;
  const int fk = (lane >> 4) * 8;
  const size_t arow0 = (size_t)blockIdx.x * 128;
  const size_t brow0 = (size_t)blockIdx.y * 128;
  const int srow = tid >> 2;         // staging: row 0..63 (+64 for 2nd chunk)
  const int skc  = (tid & 3) * 8;    // staging: k offset (elements)

  f32x4 acc[4][4] = {};

  for (int k0 = 0; k0 < K2; k0 += 32) {
    const ushort* gA0 = A + (arow0 + srow) * K2 + k0 + skc;
    const ushort* gB0 = B + (brow0 + srow) * K2 + k0 + skc;
    async16(gA0,                    &sA[tid * 8]);
    async16(gA0 + (size_t)64 * K2,  &sA[(tid + 256) * 8]);
    async16(gB0,                    &sB[tid * 8]);
    async16(gB0 + (size_t)64 * K2,  &sB[(tid + 256) * 8]);
    __syncthreads();

    bf16x8 af[4], bfr[4];
#pragma unroll
    for (int i = 0; i < 4; ++i)
      af[i] = *(const bf16x8*)&sA[(wr + i * 16 + fr) * 32 + fk];
#pragma unroll
    for (int j = 0; j < 4; ++j)
      bfr[j] = *(const bf16x8*)&sB[(wc + j * 16 + fr) * 32 + fk];
#pragma unroll
    for (int i = 0; i < 4; ++i)
#pragma unroll
      for (int j = 0; j < 4; ++j)
        acc[i][j] = __builtin_amdgcn_mfma_f32_16x16x32_bf16(af[i], bfr[j], acc[i][j], 0, 0, 0);
    __syncthreads();
  }

  const int rq = (lane >> 4) * 4;
#pragma unroll
  for (int j = 0; j < 4; ++j) {
    const size_t col = brow0 + wc + j * 16 + fr;
    const float bv = bias[col];
#pragma unroll
    for (int i = 0; i < 4; ++i) {
      const size_t row = arow0 + wr + i * 16 + rq;
#pragma unroll
      for (int r = 0; r < 4; ++r)
        C[(row + r) * Ndim + col] = acc[i][j][r] + bv;
    }
  }
}

extern "C" void kernel_launch(void* const* d_in, const int* in_sizes, int n_in,
                              void* d_out, int out_size, void* d_ws, size_t ws_size,
                              hipStream_t stream) {
  const float* x      = (const float*)d_in[0];
  const int*   qw     = (const int*)d_in[1];
  const float* wsc    = (const float*)d_in[2];
  const float* pd     = (const float*)d_in[3];
  const float* pu     = (const float*)d_in[4];
  const float* smooth = (const float*)d_in[5];
  const float* bias   = (const float*)d_in[6];
  float* out = (float*)d_out;

  const size_t abytes = (size_t)Tdim * K2 * 2;          // 34,078,720
  ushort* A   = (ushort*)d_ws;
  ushort* B   = (ushort*)((char*)d_ws + abytes);
  ushort* pdT = (ushort*)((char*)d_ws + 2 * abytes);    // 32*4096*2 = 256 KB
  float*  part= (float*)((char*)d_ws + 2 * abytes + 262144);  // 8*T*32*4 = 4 MB

  hipLaunchKernelGGL(prep_pdT_kernel,    dim3(512),    dim3(256), 0, stream, pd, pdT);
  hipLaunchKernelGGL(quant_x_kernel,     dim3(16384),  dim3(256), 0, stream, x, smooth, A);
  hipLaunchKernelGGL(lowrank_gemm_kernel,dim3(32, 8),  dim3(256), 0, stream, x, smooth, pdT, part);
  hipLaunchKernelGGL(reduce_tail_A_kernel,dim3(1024),  dim3(256), 0, stream, part, A);
  hipLaunchKernelGGL(dequant_w_kernel,   dim3(8192),   dim3(256), 0, stream, qw, wsc, B);
  hipLaunchKernelGGL(tail_B_kernel,      dim3(1024),   dim3(256), 0, stream, pu, B);
  hipLaunchKernelGGL(gemm_kernel,        dim3(32, 32), dim3(256), 0, stream, A, B, bias, out);
}

// Round 3
// 374.357 us; speedup vs baseline: 1.6767x; 1.0177x over previous
//
#include <hip/hip_runtime.h>
#include <hip/hip_bf16.h>
#include <stdint.h>

#define Tdim 4096
#define Ndim 4096
#define Kdim 4096
#define K2   4160   // 4096 + 32 (low-rank concat) + 32 (zero pad to multiple of 64)

using f32x4  = __attribute__((ext_vector_type(4))) float;
using bf16x8 = __attribute__((ext_vector_type(8))) short;

// round-to-nearest-even f32 -> bf16 bits
__device__ inline ushort f2bf(float f) {
  union { float f; unsigned u; } v; v.f = f;
  unsigned lsb = (v.u >> 16) & 1u;
  v.u += 0x7fffu + lsb;
  return (ushort)(v.u >> 16);
}

__device__ inline unsigned pack2(float a, float b) {
  return (unsigned)f2bf(a) | ((unsigned)f2bf(b) << 16);
}

__device__ inline float qd(float v, float s) {   // quantize-dequantize
  return fminf(fmaxf(rintf(v / s), -8.f), 7.f) * s;
}

__device__ inline void async16(const void* g, void* l) {
  __builtin_amdgcn_global_load_lds(
      (const __attribute__((address_space(1))) unsigned int*)g,
      (__attribute__((address_space(3))) unsigned int*)l, 16, 0, 0);
}

// ========== K1: fused activation quant-dequant + low-rank partial GEMM ======
// grid (32 token-tiles, 8 k-splits); block covers 128 tokens x 512 k.
// Writes A[token][0..4095] (bf16 qdq values) and partials[split][T][32].
__global__ __launch_bounds__(256) void prep_a_kernel(
    const float* __restrict__ x, const float* __restrict__ smooth,
    const float* __restrict__ pd, ushort* __restrict__ A,
    float* __restrict__ partials) {
  __shared__ __attribute__((aligned(16))) ushort sXS[128 * 136];  // xs (bf16) for MFMA
  __shared__ __attribute__((aligned(16))) ushort sQ[128 * 136];   // qdq(xs) for A
  const int tid  = threadIdx.x;
  const int lane = tid & 63;
  const int wave = tid >> 6;
  const int fr  = lane & 15;
  const int fkq = lane >> 4;
  const int fk  = fkq * 8;
  const int tok0 = blockIdx.x * 128;
  const int kc0  = blockIdx.y * 512;
  const int r = tid >> 1;          // token row 0..127
  const int g = tid & 1;           // which 64-group of the 128-k chunk
  const int srow2 = tid >> 2;      // A-store: row 0..63 (+64)
  const int scol2 = (tid & 3) * 8; // A-store: col

  f32x4 acc[2][2] = {};

  for (int c = 0; c < 4; ++c) {
    const int kbase = kc0 + c * 128;
    const int kcol  = g * 64;
    const float4* xp = (const float4*)&x[(size_t)(tok0 + r) * Kdim + kbase + kcol];
    const float4* sp = (const float4*)&smooth[kbase + kcol];
    float4 v[16];
#pragma unroll
    for (int q = 0; q < 16; ++q) {
      float4 xv = xp[q], sm = sp[q];
      v[q].x = xv.x * sm.x; v[q].y = xv.y * sm.y;
      v[q].z = xv.z * sm.z; v[q].w = xv.w * sm.w;
    }
    float a = 0.f;
#pragma unroll
    for (int q = 0; q < 16; ++q)
      a = fmaxf(a, fmaxf(fmaxf(fabsf(v[q].x), fabsf(v[q].y)),
                         fmaxf(fabsf(v[q].z), fabsf(v[q].w))));
    const float s = fmaxf(a / 7.0f, 1e-8f);   // exact div: must match np
#pragma unroll
    for (int q2 = 0; q2 < 8; ++q2) {
      const float4 v0 = v[2 * q2], v1 = v[2 * q2 + 1];
      uint4 wx, wq;
      wx.x = pack2(v0.x, v0.y);           wx.y = pack2(v0.z, v0.w);
      wx.z = pack2(v1.x, v1.y);           wx.w = pack2(v1.z, v1.w);
      wq.x = pack2(qd(v0.x, s), qd(v0.y, s)); wq.y = pack2(qd(v0.z, s), qd(v0.w, s));
      wq.z = pack2(qd(v1.x, s), qd(v1.y, s)); wq.w = pack2(qd(v1.z, s), qd(v1.w, s));
      *(uint4*)&sXS[r * 136 + kcol + q2 * 8] = wx;
      *(uint4*)&sQ [r * 136 + kcol + q2 * 8] = wq;
    }
    __syncthreads();

    // low-rank MFMA: t_partial += xs_tile @ pd_tile (pd fragments built inline)
#pragma unroll
    for (int kk = 0; kk < 4; ++kk) {
      bf16x8 af0 = *(const bf16x8*)&sXS[(wave * 32 + fr) * 136 + kk * 32 + fk];
      bf16x8 af1 = *(const bf16x8*)&sXS[(wave * 32 + 16 + fr) * 136 + kk * 32 + fk];
      bf16x8 b0, b1;
#pragma unroll
      for (int e = 0; e < 8; ++e) {
        const size_t kr = (size_t)(kbase + kk * 32 + fk + e) * 32;
        b0[e] = (short)f2bf(pd[kr + fr]);
        b1[e] = (short)f2bf(pd[kr + 16 + fr]);
      }
      acc[0][0] = __builtin_amdgcn_mfma_f32_16x16x32_bf16(af0, b0, acc[0][0], 0, 0, 0);
      acc[0][1] = __builtin_amdgcn_mfma_f32_16x16x32_bf16(af0, b1, acc[0][1], 0, 0, 0);
      acc[1][0] = __builtin_amdgcn_mfma_f32_16x16x32_bf16(af1, b0, acc[1][0], 0, 0, 0);
      acc[1][1] = __builtin_amdgcn_mfma_f32_16x16x32_bf16(af1, b1, acc[1][1], 0, 0, 0);
    }

    // coalesced A store from sQ
#pragma unroll
    for (int h = 0; h < 2; ++h) {
      const int rr = srow2 + h * 64;
#pragma unroll
      for (int u = 0; u < 4; ++u)
        *(uint4*)&A[(size_t)(tok0 + rr) * K2 + kbase + scol2 + u * 32] =
            *(const uint4*)&sQ[rr * 136 + scol2 + u * 32];
    }
    __syncthreads();
  }

  float* P = partials + (size_t)blockIdx.y * Tdim * 32;
#pragma unroll
  for (int i = 0; i < 2; ++i) {
    const int row0 = tok0 + wave * 32 + i * 16 + fkq * 4;
#pragma unroll
    for (int j = 0; j < 2; ++j) {
      const int col = j * 16 + fr;
#pragma unroll
      for (int rr = 0; rr < 4; ++rr)
        P[(size_t)(row0 + rr) * 32 + col] = acc[i][j][rr];
    }
  }
}

// ====== K2: weight dequant (bid<8192) | A-tail reduce (8192..9215) | B-tail ==
__global__ __launch_bounds__(256) void wprep_kernel(
    const int* __restrict__ qw, const float* __restrict__ wsc,
    const float* __restrict__ partials, const float* __restrict__ pu,
    ushort* __restrict__ A, ushort* __restrict__ B) {
  const int bid = blockIdx.x;
  if (bid < 8192) {
    // dequantize int4 weights -> B' bf16, 8 elems/thread
    const size_t idx = ((size_t)bid * 256 + threadIdx.x) * 8;
    const int n = (int)(idx >> 12);
    const int k = (int)(idx & 4095);
    const float s = wsc[n * 64 + (k >> 6)];
    const int4 q0 = *(const int4*)(qw + idx);
    const int4 q1 = *(const int4*)(qw + idx + 4);
    uint4 o;
    o.x = pack2((float)q0.x * s, (float)q0.y * s);
    o.y = pack2((float)q0.z * s, (float)q0.w * s);
    o.z = pack2((float)q1.x * s, (float)q1.y * s);
    o.w = pack2((float)q1.z * s, (float)q1.w * s);
    *(uint4*)(B + (size_t)n * K2 + k) = o;
  } else if (bid < 8192 + 1024) {
    // reduce K-split partials -> bf16 into A tail cols [4096..4160)
    const int idx = (bid - 8192) * 256 + threadIdx.x;   // T*64 threads
    const int token = idx >> 6, c = idx & 63;
    ushort v = 0;
    if (c < 32) {
      float s = 0.f;
#pragma unroll
      for (int p = 0; p < 8; ++p)
        s += partials[(size_t)p * Tdim * 32 + (size_t)token * 32 + c];
      v = f2bf(s);
    }
    A[(size_t)token * K2 + Kdim + c] = v;
  } else {
    // B tail cols = [bf16(pu^T) | zeros]
    const int idx = (bid - 9216) * 256 + threadIdx.x;   // N*64 threads
    const int n = idx >> 6, c = idx & 63;
    ushort v = 0;
    if (c < 32) v = f2bf(pu[(size_t)c * Ndim + n]);     // proj_up is [32, N]
    B[(size_t)n * K2 + Kdim + c] = v;
  }
}

// ========== K3: C = A' @ B'^T + bias  (m97 structure, BK=64 dual-panel) =====
__global__ __launch_bounds__(256) void gemm_kernel(
    const ushort* __restrict__ A, const ushort* __restrict__ B,
    const float* __restrict__ bias, float* __restrict__ C) {
  __shared__ __attribute__((aligned(16))) ushort sA[2 * 128 * 32];  // 16 KB
  __shared__ __attribute__((aligned(16))) ushort sB[2 * 128 * 32];  // 16 KB
  const int tid  = threadIdx.x;
  const int lane = tid & 63;
  const int wave = tid >> 6;
  const int wr = (wave >> 1) * 64;
  const int wc = (wave & 1) * 64;
  const int fr = lane & 15;
  const int fk = (lane >> 4) * 8;
  const size_t arow0 = (size_t)blockIdx.x * 128;
  const size_t brow0 = (size_t)blockIdx.y * 128;
  const int srow = tid >> 2;          // 0..63
  const int skc  = (tid & 3) * 8;

  const ushort* gA = A + (arow0 + srow) * K2 + skc;
  const ushort* gB = B + (brow0 + srow) * K2 + skc;

  f32x4 acc[4][4] = {};

  for (int k0 = 0; k0 < K2; k0 += 64) {
    // stage two BK=32 panels: [panel][128 rows][32 cols]
#pragma unroll
    for (int p = 0; p < 2; ++p) {
      async16(gA + p * 32,                   &sA[p * 4096 + tid * 8]);
      async16(gA + p * 32 + (size_t)64 * K2, &sA[p * 4096 + (tid + 256) * 8]);
      async16(gB + p * 32,                   &sB[p * 4096 + tid * 8]);
      async16(gB + p * 32 + (size_t)64 * K2, &sB[p * 4096 + (tid + 256) * 8]);
    }
    gA += 64; gB += 64;
    __syncthreads();

#pragma unroll
    for (int kk = 0; kk < 2; ++kk) {
      bf16x8 af[4], bfr[4];
#pragma unroll
      for (int i = 0; i < 4; ++i)
        af[i] = *(const bf16x8*)&sA[kk * 4096 + (wr + i * 16 + fr) * 32 + fk];
#pragma unroll
      for (int j = 0; j < 4; ++j)
        bfr[j] = *(const bf16x8*)&sB[kk * 4096 + (wc + j * 16 + fr) * 32 + fk];
#pragma unroll
      for (int i = 0; i < 4; ++i)
#pragma unroll
        for (int j = 0; j < 4; ++j)
          acc[i][j] = __builtin_amdgcn_mfma_f32_16x16x32_bf16(af[i], bfr[j], acc[i][j], 0, 0, 0);
    }
    __syncthreads();
  }

  const int rq = (lane >> 4) * 4;
#pragma unroll
  for (int j = 0; j < 4; ++j) {
    const size_t col = brow0 + wc + j * 16 + fr;
    const float bv = bias[col];
#pragma unroll
    for (int i = 0; i < 4; ++i) {
      const size_t row = arow0 + wr + i * 16 + rq;
#pragma unroll
      for (int r = 0; r < 4; ++r)
        C[(row + r) * Ndim + col] = acc[i][j][r] + bv;
    }
  }
}

extern "C" void kernel_launch(void* const* d_in, const int* in_sizes, int n_in,
                              void* d_out, int out_size, void* d_ws, size_t ws_size,
                              hipStream_t stream) {
  const float* x      = (const float*)d_in[0];
  const int*   qw     = (const int*)d_in[1];
  const float* wsc    = (const float*)d_in[2];
  const float* pd     = (const float*)d_in[3];
  const float* pu     = (const float*)d_in[4];
  const float* smooth = (const float*)d_in[5];
  const float* bias   = (const float*)d_in[6];
  float* out = (float*)d_out;

  const size_t abytes = (size_t)Tdim * K2 * 2;          // 34,078,720
  ushort* A    = (ushort*)d_ws;
  ushort* B    = (ushort*)((char*)d_ws + abytes);
  float*  part = (float*)((char*)d_ws + 2 * abytes);    // 8*T*32*4 = 4 MB

  hipLaunchKernelGGL(prep_a_kernel, dim3(32, 8),  dim3(256), 0, stream, x, smooth, pd, A, part);
  hipLaunchKernelGGL(wprep_kernel,  dim3(10240),  dim3(256), 0, stream, qw, wsc, part, pu, A, B);
  hipLaunchKernelGGL(gemm_kernel,   dim3(32, 32), dim3(256), 0, stream, A, B, bias, out);
}

// Round 4
// 371.141 us; speedup vs baseline: 1.6912x; 1.0087x over previous
//
#include <hip/hip_runtime.h>
#include <hip/hip_bf16.h>
#include <stdint.h>

#define Tdim 4096
#define Ndim 4096
#define Kdim 4096
#define K2   4160   // 4096 + 32 (low-rank concat) + 32 (zero pad to multiple of 64)

using f32x4  = __attribute__((ext_vector_type(4))) float;
using bf16x8 = __attribute__((ext_vector_type(8))) short;

// round-to-nearest-even f32 -> bf16 bits
__device__ inline ushort f2bf(float f) {
  union { float f; unsigned u; } v; v.f = f;
  unsigned lsb = (v.u >> 16) & 1u;
  v.u += 0x7fffu + lsb;
  return (ushort)(v.u >> 16);
}

__device__ inline unsigned pack2(float a, float b) {
  return (unsigned)f2bf(a) | ((unsigned)f2bf(b) << 16);
}

__device__ inline float qd(float v, float s) {   // quantize-dequantize
  return fminf(fmaxf(rintf(v / s), -8.f), 7.f) * s;
}

__device__ inline void async16(const void* g, void* l) {
  __builtin_amdgcn_global_load_lds(
      (const __attribute__((address_space(1))) unsigned int*)g,
      (__attribute__((address_space(3))) unsigned int*)l, 16, 0, 0);
}

// ========== K1: fused activation quant-dequant + low-rank partial GEMM ======
// grid (32 token-tiles, 8 k-splits); block covers 128 tokens x 512 k.
// Writes A[token][0..4095] (bf16 qdq values) and partials[split][T][32].
__global__ __launch_bounds__(256) void prep_a_kernel(
    const float* __restrict__ x, const float* __restrict__ smooth,
    const float* __restrict__ pd, ushort* __restrict__ A,
    float* __restrict__ partials) {
  __shared__ __attribute__((aligned(16))) ushort sXS[128 * 136];  // xs (bf16) for MFMA
  __shared__ __attribute__((aligned(16))) ushort sQ[128 * 136];   // qdq(xs) for A
  const int tid  = threadIdx.x;
  const int lane = tid & 63;
  const int wave = tid >> 6;
  const int fr  = lane & 15;
  const int fkq = lane >> 4;
  const int fk  = fkq * 8;
  const int tok0 = blockIdx.x * 128;
  const int kc0  = blockIdx.y * 512;
  const int r = tid >> 1;          // token row 0..127
  const int g = tid & 1;           // which 64-group of the 128-k chunk
  const int srow2 = tid >> 2;      // A-store: row 0..63 (+64)
  const int scol2 = (tid & 3) * 8; // A-store: col

  f32x4 acc[2][2] = {};

  for (int c = 0; c < 4; ++c) {
    const int kbase = kc0 + c * 128;
    const int kcol  = g * 64;
    const float4* xp = (const float4*)&x[(size_t)(tok0 + r) * Kdim + kbase + kcol];
    const float4* sp = (const float4*)&smooth[kbase + kcol];
    float4 v[16];
#pragma unroll
    for (int q = 0; q < 16; ++q) {
      float4 xv = xp[q], sm = sp[q];
      v[q].x = xv.x * sm.x; v[q].y = xv.y * sm.y;
      v[q].z = xv.z * sm.z; v[q].w = xv.w * sm.w;
    }
    float a = 0.f;
#pragma unroll
    for (int q = 0; q < 16; ++q)
      a = fmaxf(a, fmaxf(fmaxf(fabsf(v[q].x), fabsf(v[q].y)),
                         fmaxf(fabsf(v[q].z), fabsf(v[q].w))));
    const float s = fmaxf(a / 7.0f, 1e-8f);   // exact div: must match np
#pragma unroll
    for (int q2 = 0; q2 < 8; ++q2) {
      const float4 v0 = v[2 * q2], v1 = v[2 * q2 + 1];
      uint4 wx, wq;
      wx.x = pack2(v0.x, v0.y);           wx.y = pack2(v0.z, v0.w);
      wx.z = pack2(v1.x, v1.y);           wx.w = pack2(v1.z, v1.w);
      wq.x = pack2(qd(v0.x, s), qd(v0.y, s)); wq.y = pack2(qd(v0.z, s), qd(v0.w, s));
      wq.z = pack2(qd(v1.x, s), qd(v1.y, s)); wq.w = pack2(qd(v1.z, s), qd(v1.w, s));
      *(uint4*)&sXS[r * 136 + kcol + q2 * 8] = wx;
      *(uint4*)&sQ [r * 136 + kcol + q2 * 8] = wq;
    }
    __syncthreads();

    // low-rank MFMA: t_partial += xs_tile @ pd_tile (pd fragments built inline)
#pragma unroll
    for (int kk = 0; kk < 4; ++kk) {
      bf16x8 af0 = *(const bf16x8*)&sXS[(wave * 32 + fr) * 136 + kk * 32 + fk];
      bf16x8 af1 = *(const bf16x8*)&sXS[(wave * 32 + 16 + fr) * 136 + kk * 32 + fk];
      bf16x8 b0, b1;
#pragma unroll
      for (int e = 0; e < 8; ++e) {
        const size_t kr = (size_t)(kbase + kk * 32 + fk + e) * 32;
        b0[e] = (short)f2bf(pd[kr + fr]);
        b1[e] = (short)f2bf(pd[kr + 16 + fr]);
      }
      acc[0][0] = __builtin_amdgcn_mfma_f32_16x16x32_bf16(af0, b0, acc[0][0], 0, 0, 0);
      acc[0][1] = __builtin_amdgcn_mfma_f32_16x16x32_bf16(af0, b1, acc[0][1], 0, 0, 0);
      acc[1][0] = __builtin_amdgcn_mfma_f32_16x16x32_bf16(af1, b0, acc[1][0], 0, 0, 0);
      acc[1][1] = __builtin_amdgcn_mfma_f32_16x16x32_bf16(af1, b1, acc[1][1], 0, 0, 0);
    }

    // coalesced A store from sQ
#pragma unroll
    for (int h = 0; h < 2; ++h) {
      const int rr = srow2 + h * 64;
#pragma unroll
      for (int u = 0; u < 4; ++u)
        *(uint4*)&A[(size_t)(tok0 + rr) * K2 + kbase + scol2 + u * 32] =
            *(const uint4*)&sQ[rr * 136 + scol2 + u * 32];
    }
    __syncthreads();
  }

  float* P = partials + (size_t)blockIdx.y * Tdim * 32;
#pragma unroll
  for (int i = 0; i < 2; ++i) {
    const int row0 = tok0 + wave * 32 + i * 16 + fkq * 4;
#pragma unroll
    for (int j = 0; j < 2; ++j) {
      const int col = j * 16 + fr;
#pragma unroll
      for (int rr = 0; rr < 4; ++rr)
        P[(size_t)(row0 + rr) * 32 + col] = acc[i][j][rr];
    }
  }
}

// ====== K2: weight dequant (bid<8192) | A-tail reduce (8192..9215) | B-tail ==
__global__ __launch_bounds__(256) void wprep_kernel(
    const int* __restrict__ qw, const float* __restrict__ wsc,
    const float* __restrict__ partials, const float* __restrict__ pu,
    ushort* __restrict__ A, ushort* __restrict__ B) {
  const int bid = blockIdx.x;
  if (bid < 8192) {
    // dequantize int4 weights -> B' bf16, 8 elems/thread
    const size_t idx = ((size_t)bid * 256 + threadIdx.x) * 8;
    const int n = (int)(idx >> 12);
    const int k = (int)(idx & 4095);
    const float s = wsc[n * 64 + (k >> 6)];
    const int4 q0 = *(const int4*)(qw + idx);
    const int4 q1 = *(const int4*)(qw + idx + 4);
    uint4 o;
    o.x = pack2((float)q0.x * s, (float)q0.y * s);
    o.y = pack2((float)q0.z * s, (float)q0.w * s);
    o.z = pack2((float)q1.x * s, (float)q1.y * s);
    o.w = pack2((float)q1.z * s, (float)q1.w * s);
    *(uint4*)(B + (size_t)n * K2 + k) = o;
  } else if (bid < 8192 + 1024) {
    // reduce K-split partials -> bf16 into A tail cols [4096..4160)
    const int idx = (bid - 8192) * 256 + threadIdx.x;   // T*64 threads
    const int token = idx >> 6, c = idx & 63;
    ushort v = 0;
    if (c < 32) {
      float s = 0.f;
#pragma unroll
      for (int p = 0; p < 8; ++p)
        s += partials[(size_t)p * Tdim * 32 + (size_t)token * 32 + c];
      v = f2bf(s);
    }
    A[(size_t)token * K2 + Kdim + c] = v;
  } else {
    // B tail cols = [bf16(pu^T) | zeros]
    const int idx = (bid - 9216) * 256 + threadIdx.x;   // N*64 threads
    const int n = idx >> 6, c = idx & 63;
    ushort v = 0;
    if (c < 32) v = f2bf(pu[(size_t)c * Ndim + n]);     // proj_up is [32, N]
    B[(size_t)n * K2 + Kdim + c] = v;
  }
}

// ========== K3: C = A' @ B'^T + bias  (BK=64 dual-panel, XOR-swizzled LDS) ==
// LDS layout: slot (row r, chunk c') holds global 16B-chunk c = c' ^ ((r>>1)&3).
// Staging keeps the async16 lane-contiguous dst; only the global source chunk
// is permuted per lane (coalescing unchanged: each 4-lane group still covers
// the same 64 B). Fragment reads XOR with ((fr>>1)&3) -> every 8 consecutive
// lanes hit all 32 banks; only free 2-way aliasing remains (m136).
__global__ __launch_bounds__(256) void gemm_kernel(
    const ushort* __restrict__ A, const ushort* __restrict__ B,
    const float* __restrict__ bias, float* __restrict__ C) {
  __shared__ __attribute__((aligned(16))) ushort sA[2 * 128 * 32];  // 16 KB
  __shared__ __attribute__((aligned(16))) ushort sB[2 * 128 * 32];  // 16 KB
  const int tid  = threadIdx.x;
  const int lane = tid & 63;
  const int wave = tid >> 6;
  const int wr = (wave >> 1) * 64;
  const int wc = (wave & 1) * 64;
  const int fr = lane & 15;
  const size_t arow0 = (size_t)blockIdx.x * 128;
  const size_t brow0 = (size_t)blockIdx.y * 128;
  const int srow = tid >> 2;          // 0..63
  const int cs   = tid & 3;           // LDS chunk this lane fills
  const int skc  = (cs ^ ((srow >> 1) & 3)) * 8;   // swizzled global source chunk
  // swizzled fragment chunk (lane-constant): global chunk cf = lane>>4
  const int fchunk = (((lane >> 4) ^ ((fr >> 1) & 3))) * 8;

  const ushort* gA = A + (arow0 + srow) * K2 + skc;
  const ushort* gB = B + (brow0 + srow) * K2 + skc;

  f32x4 acc[4][4] = {};

  for (int k0 = 0; k0 < K2; k0 += 64) {
    // stage two BK=32 panels: [panel][128 rows][32 cols]
#pragma unroll
    for (int p = 0; p < 2; ++p) {
      async16(gA + p * 32,                   &sA[p * 4096 + tid * 8]);
      async16(gA + p * 32 + (size_t)64 * K2, &sA[p * 4096 + (tid + 256) * 8]);
      async16(gB + p * 32,                   &sB[p * 4096 + tid * 8]);
      async16(gB + p * 32 + (size_t)64 * K2, &sB[p * 4096 + (tid + 256) * 8]);
    }
    gA += 64; gB += 64;
    __syncthreads();

#pragma unroll
    for (int kk = 0; kk < 2; ++kk) {
      bf16x8 af[4], bfr[4];
#pragma unroll
      for (int i = 0; i < 4; ++i)
        af[i] = *(const bf16x8*)&sA[kk * 4096 + (wr + i * 16 + fr) * 32 + fchunk];
#pragma unroll
      for (int j = 0; j < 4; ++j)
        bfr[j] = *(const bf16x8*)&sB[kk * 4096 + (wc + j * 16 + fr) * 32 + fchunk];
#pragma unroll
      for (int i = 0; i < 4; ++i)
#pragma unroll
        for (int j = 0; j < 4; ++j)
          acc[i][j] = __builtin_amdgcn_mfma_f32_16x16x32_bf16(af[i], bfr[j], acc[i][j], 0, 0, 0);
    }
    __syncthreads();
  }

  const int rq = (lane >> 4) * 4;
#pragma unroll
  for (int j = 0; j < 4; ++j) {
    const size_t col = brow0 + wc + j * 16 + fr;
    const float bv = bias[col];
#pragma unroll
    for (int i = 0; i < 4; ++i) {
      const size_t row = arow0 + wr + i * 16 + rq;
#pragma unroll
      for (int r = 0; r < 4; ++r)
        C[(row + r) * Ndim + col] = acc[i][j][r] + bv;
    }
  }
}

extern "C" void kernel_launch(void* const* d_in, const int* in_sizes, int n_in,
                              void* d_out, int out_size, void* d_ws, size_t ws_size,
                              hipStream_t stream) {
  const float* x      = (const float*)d_in[0];
  const int*   qw     = (const int*)d_in[1];
  const float* wsc    = (const float*)d_in[2];
  const float* pd     = (const float*)d_in[3];
  const float* pu     = (const float*)d_in[4];
  const float* smooth = (const float*)d_in[5];
  const float* bias   = (const float*)d_in[6];
  float* out = (float*)d_out;

  const size_t abytes = (size_t)Tdim * K2 * 2;          // 34,078,720
  ushort* A    = (ushort*)d_ws;
  ushort* B    = (ushort*)((char*)d_ws + abytes);
  float*  part = (float*)((char*)d_ws + 2 * abytes);    // 8*T*32*4 = 4 MB

  hipLaunchKernelGGL(prep_a_kernel, dim3(32, 8),  dim3(256), 0, stream, x, smooth, pd, A, part);
  hipLaunchKernelGGL(wprep_kernel,  dim3(10240),  dim3(256), 0, stream, qw, wsc, part, pu, A, B);
  hipLaunchKernelGGL(gemm_kernel,   dim3(32, 32), dim3(256), 0, stream, A, B, bias, out);
}

// Round 5
// 357.835 us; speedup vs baseline: 1.7541x; 1.0372x over previous
//
#include <hip/hip_runtime.h>
#include <hip/hip_bf16.h>
#include <stdint.h>

#define Tdim 4096
#define Ndim 4096
#define Kdim 4096
#define K2   4160   // 4096 + 32 (low-rank concat) + 32 (zero pad to multiple of 64)
#define NSPLIT 16   // K-splits for the low-rank partial GEMM

using f32x4  = __attribute__((ext_vector_type(4))) float;
using bf16x8 = __attribute__((ext_vector_type(8))) short;

// round-to-nearest-even f32 -> bf16 bits
__device__ inline ushort f2bf(float f) {
  union { float f; unsigned u; } v; v.f = f;
  unsigned lsb = (v.u >> 16) & 1u;
  v.u += 0x7fffu + lsb;
  return (ushort)(v.u >> 16);
}

__device__ inline unsigned pack2(float a, float b) {
  return (unsigned)f2bf(a) | ((unsigned)f2bf(b) << 16);
}

__device__ inline float qd(float v, float s) {   // quantize-dequantize
  return fminf(fmaxf(rintf(v / s), -8.f), 7.f) * s;
}

__device__ inline void async16(const void* g, void* l) {
  __builtin_amdgcn_global_load_lds(
      (const __attribute__((address_space(1))) unsigned int*)g,
      (__attribute__((address_space(3))) unsigned int*)l, 16, 0, 0);
}

// ---------------- K0: pdT[n][k] = bf16(pd[k][n])  (32 x 4096) ---------------
__global__ __launch_bounds__(256) void prep_pdT_kernel(
    const float* __restrict__ pd, ushort* __restrict__ pdT) {
  const int idx = blockIdx.x * 256 + threadIdx.x;   // 32*4096 threads
  const int n = idx >> 12;
  const int k = idx & 4095;
  pdT[(size_t)n * Kdim + k] = f2bf(pd[(size_t)k * 32 + n]);
}

// ========== K1: fused activation quant-dequant + low-rank partial GEMM ======
// grid (32 token-tiles, 16 k-splits); block covers 128 tokens x 256 k.
// Writes A[token][0..4095] (bf16 qdq values) and partials[split][T][32].
__global__ __launch_bounds__(256) void prep_a_kernel(
    const float* __restrict__ x, const float* __restrict__ smooth,
    const ushort* __restrict__ pdT, ushort* __restrict__ A,
    float* __restrict__ partials) {
  __shared__ __attribute__((aligned(16))) ushort sXS[128 * 136];  // xs (bf16) for MFMA
  __shared__ __attribute__((aligned(16))) ushort sQ[128 * 136];   // qdq(xs) for A
  const int tid  = threadIdx.x;
  const int lane = tid & 63;
  const int wave = tid >> 6;
  const int fr  = lane & 15;
  const int fkq = lane >> 4;
  const int fk  = fkq * 8;
  const int tok0 = blockIdx.x * 128;
  const int kc0  = blockIdx.y * 256;
  const int r = tid >> 1;          // token row 0..127
  const int g = tid & 1;           // which 64-group of the 128-k chunk
  const int srow2 = tid >> 2;      // A-store: row 0..63 (+64)
  const int scol2 = (tid & 3) * 8; // A-store: col

  f32x4 acc[2][2] = {};

  for (int c = 0; c < 2; ++c) {
    const int kbase = kc0 + c * 128;
    const int kcol  = g * 64;
    const float4* xp = (const float4*)&x[(size_t)(tok0 + r) * Kdim + kbase + kcol];
    const float4* sp = (const float4*)&smooth[kbase + kcol];
    float4 v[16];
#pragma unroll
    for (int q = 0; q < 16; ++q) {
      float4 xv = xp[q], sm = sp[q];
      v[q].x = xv.x * sm.x; v[q].y = xv.y * sm.y;
      v[q].z = xv.z * sm.z; v[q].w = xv.w * sm.w;
    }
    float a = 0.f;
#pragma unroll
    for (int q = 0; q < 16; ++q)
      a = fmaxf(a, fmaxf(fmaxf(fabsf(v[q].x), fabsf(v[q].y)),
                         fmaxf(fabsf(v[q].z), fabsf(v[q].w))));
    const float s = fmaxf(a / 7.0f, 1e-8f);   // exact div: must match np
#pragma unroll
    for (int q2 = 0; q2 < 8; ++q2) {
      const float4 v0 = v[2 * q2], v1 = v[2 * q2 + 1];
      uint4 wx, wq;
      wx.x = pack2(v0.x, v0.y);           wx.y = pack2(v0.z, v0.w);
      wx.z = pack2(v1.x, v1.y);           wx.w = pack2(v1.z, v1.w);
      wq.x = pack2(qd(v0.x, s), qd(v0.y, s)); wq.y = pack2(qd(v0.z, s), qd(v0.w, s));
      wq.z = pack2(qd(v1.x, s), qd(v1.y, s)); wq.w = pack2(qd(v1.z, s), qd(v1.w, s));
      *(uint4*)&sXS[r * 136 + kcol + q2 * 8] = wx;
      *(uint4*)&sQ [r * 136 + kcol + q2 * 8] = wq;
    }
    __syncthreads();

    // low-rank MFMA: t_partial += xs_tile @ pdT_tile (B fragments via vec loads)
#pragma unroll
    for (int kk = 0; kk < 4; ++kk) {
      const int kglob = kbase + kk * 32 + fk;
      bf16x8 af0 = *(const bf16x8*)&sXS[(wave * 32 + fr) * 136 + kk * 32 + fk];
      bf16x8 af1 = *(const bf16x8*)&sXS[(wave * 32 + 16 + fr) * 136 + kk * 32 + fk];
      bf16x8 b0 = *(const bf16x8*)&pdT[(size_t)fr * Kdim + kglob];
      bf16x8 b1 = *(const bf16x8*)&pdT[(size_t)(16 + fr) * Kdim + kglob];
      acc[0][0] = __builtin_amdgcn_mfma_f32_16x16x32_bf16(af0, b0, acc[0][0], 0, 0, 0);
      acc[0][1] = __builtin_amdgcn_mfma_f32_16x16x32_bf16(af0, b1, acc[0][1], 0, 0, 0);
      acc[1][0] = __builtin_amdgcn_mfma_f32_16x16x32_bf16(af1, b0, acc[1][0], 0, 0, 0);
      acc[1][1] = __builtin_amdgcn_mfma_f32_16x16x32_bf16(af1, b1, acc[1][1], 0, 0, 0);
    }

    // coalesced A store from sQ
#pragma unroll
    for (int h = 0; h < 2; ++h) {
      const int rr = srow2 + h * 64;
#pragma unroll
      for (int u = 0; u < 4; ++u)
        *(uint4*)&A[(size_t)(tok0 + rr) * K2 + kbase + scol2 + u * 32] =
            *(const uint4*)&sQ[rr * 136 + scol2 + u * 32];
    }
    __syncthreads();
  }

  float* P = partials + (size_t)blockIdx.y * Tdim * 32;
#pragma unroll
  for (int i = 0; i < 2; ++i) {
    const int row0 = tok0 + wave * 32 + i * 16 + fkq * 4;
#pragma unroll
    for (int j = 0; j < 2; ++j) {
      const int col = j * 16 + fr;
#pragma unroll
      for (int rr = 0; rr < 4; ++rr)
        P[(size_t)(row0 + rr) * 32 + col] = acc[i][j][rr];
    }
  }
}

// ====== K2: weight dequant (bid<8192) | A-tail reduce (8192..9215) | B-tail ==
__global__ __launch_bounds__(256) void wprep_kernel(
    const int* __restrict__ qw, const float* __restrict__ wsc,
    const float* __restrict__ partials, const float* __restrict__ pu,
    ushort* __restrict__ A, ushort* __restrict__ B) {
  const int bid = blockIdx.x;
  if (bid < 8192) {
    // dequantize int4 weights -> B' bf16, 8 elems/thread
    const size_t idx = ((size_t)bid * 256 + threadIdx.x) * 8;
    const int n = (int)(idx >> 12);
    const int k = (int)(idx & 4095);
    const float s = wsc[n * 64 + (k >> 6)];
    const int4 q0 = *(const int4*)(qw + idx);
    const int4 q1 = *(const int4*)(qw + idx + 4);
    uint4 o;
    o.x = pack2((float)q0.x * s, (float)q0.y * s);
    o.y = pack2((float)q0.z * s, (float)q0.w * s);
    o.z = pack2((float)q1.x * s, (float)q1.y * s);
    o.w = pack2((float)q1.z * s, (float)q1.w * s);
    *(uint4*)(B + (size_t)n * K2 + k) = o;
  } else if (bid < 8192 + 1024) {
    // reduce K-split partials -> bf16 into A tail cols [4096..4160)
    const int idx = (bid - 8192) * 256 + threadIdx.x;   // T*64 threads
    const int token = idx >> 6, c = idx & 63;
    ushort v = 0;
    if (c < 32) {
      float s = 0.f;
#pragma unroll
      for (int p = 0; p < NSPLIT; ++p)
        s += partials[(size_t)p * Tdim * 32 + (size_t)token * 32 + c];
      v = f2bf(s);
    }
    A[(size_t)token * K2 + Kdim + c] = v;
  } else {
    // B tail cols = [bf16(pu^T) | zeros]
    const int idx = (bid - 9216) * 256 + threadIdx.x;   // N*64 threads
    const int n = idx >> 6, c = idx & 63;
    ushort v = 0;
    if (c < 32) v = f2bf(pu[(size_t)c * Ndim + n]);     // proj_up is [32, N]
    B[(size_t)n * K2 + Kdim + c] = v;
  }
}

// ========== K3: C = A' @ B'^T + bias  (BK=64 dual-panel, XOR-swizzled LDS) ==
// LDS layout: slot (row r, chunk c') holds global 16B-chunk c = c' ^ ((r>>1)&3).
// Block remap: 8x8 super-tiles so concurrently-resident blocks share panels
// (working set 17 MB/64 blocks instead of 34 MB) -> better L2/L3 reuse.
__global__ __launch_bounds__(256) void gemm_kernel(
    const ushort* __restrict__ A, const ushort* __restrict__ B,
    const float* __restrict__ bias, float* __restrict__ C) {
  __shared__ __attribute__((aligned(16))) ushort sA[2 * 128 * 32];  // 16 KB
  __shared__ __attribute__((aligned(16))) ushort sB[2 * 128 * 32];  // 16 KB
  const int tid  = threadIdx.x;
  const int lane = tid & 63;
  const int wave = tid >> 6;
  const int wr = (wave >> 1) * 64;
  const int wc = (wave & 1) * 64;
  const int fr = lane & 15;

  // 8x8 super-tile block swizzle (pure permutation of the 32x32 block grid)
  const int bid    = blockIdx.y * 32 + blockIdx.x;
  const int super  = bid >> 6;          // 0..15
  const int within = bid & 63;
  const int brow   = (super >> 2) * 8 + (within >> 3);
  const int bcol   = (super & 3) * 8 + (within & 7);
  const size_t arow0 = (size_t)brow * 128;
  const size_t brow0 = (size_t)bcol * 128;

  const int srow = tid >> 2;          // 0..63
  const int cs   = tid & 3;           // LDS chunk this lane fills
  const int skc  = (cs ^ ((srow >> 1) & 3)) * 8;   // swizzled global source chunk
  const int fchunk = (((lane >> 4) ^ ((fr >> 1) & 3))) * 8;

  const ushort* gA = A + (arow0 + srow) * K2 + skc;
  const ushort* gB = B + (brow0 + srow) * K2 + skc;

  f32x4 acc[4][4] = {};

  for (int k0 = 0; k0 < K2; k0 += 64) {
    // stage two BK=32 panels: [panel][128 rows][32 cols]
#pragma unroll
    for (int p = 0; p < 2; ++p) {
      async16(gA + p * 32,                   &sA[p * 4096 + tid * 8]);
      async16(gA + p * 32 + (size_t)64 * K2, &sA[p * 4096 + (tid + 256) * 8]);
      async16(gB + p * 32,                   &sB[p * 4096 + tid * 8]);
      async16(gB + p * 32 + (size_t)64 * K2, &sB[p * 4096 + (tid + 256) * 8]);
    }
    gA += 64; gB += 64;
    __syncthreads();

#pragma unroll
    for (int kk = 0; kk < 2; ++kk) {
      bf16x8 af[4], bfr[4];
#pragma unroll
      for (int i = 0; i < 4; ++i)
        af[i] = *(const bf16x8*)&sA[kk * 4096 + (wr + i * 16 + fr) * 32 + fchunk];
#pragma unroll
      for (int j = 0; j < 4; ++j)
        bfr[j] = *(const bf16x8*)&sB[kk * 4096 + (wc + j * 16 + fr) * 32 + fchunk];
#pragma unroll
      for (int i = 0; i < 4; ++i)
#pragma unroll
        for (int j = 0; j < 4; ++j)
          acc[i][j] = __builtin_amdgcn_mfma_f32_16x16x32_bf16(af[i], bfr[j], acc[i][j], 0, 0, 0);
    }
    __syncthreads();
  }

  const int rq = (lane >> 4) * 4;
#pragma unroll
  for (int j = 0; j < 4; ++j) {
    const size_t col = brow0 + wc + j * 16 + fr;
    const float bv = bias[col];
#pragma unroll
    for (int i = 0; i < 4; ++i) {
      const size_t row = arow0 + wr + i * 16 + rq;
#pragma unroll
      for (int r = 0; r < 4; ++r)
        C[(row + r) * Ndim + col] = acc[i][j][r] + bv;
    }
  }
}

extern "C" void kernel_launch(void* const* d_in, const int* in_sizes, int n_in,
                              void* d_out, int out_size, void* d_ws, size_t ws_size,
                              hipStream_t stream) {
  const float* x      = (const float*)d_in[0];
  const int*   qw     = (const int*)d_in[1];
  const float* wsc    = (const float*)d_in[2];
  const float* pd     = (const float*)d_in[3];
  const float* pu     = (const float*)d_in[4];
  const float* smooth = (const float*)d_in[5];
  const float* bias   = (const float*)d_in[6];
  float* out = (float*)d_out;

  const size_t abytes = (size_t)Tdim * K2 * 2;          // 34,078,720
  ushort* A    = (ushort*)d_ws;
  ushort* B    = (ushort*)((char*)d_ws + abytes);
  ushort* pdT  = (ushort*)((char*)d_ws + 2 * abytes);   // 32*4096*2 = 256 KB
  float*  part = (float*)((char*)d_ws + 2 * abytes + 262144);  // 16*T*32*4 = 8 MB

  hipLaunchKernelGGL(prep_pdT_kernel, dim3(512),    dim3(256), 0, stream, pd, pdT);
  hipLaunchKernelGGL(prep_a_kernel,   dim3(32, NSPLIT), dim3(256), 0, stream, x, smooth, pdT, A, part);
  hipLaunchKernelGGL(wprep_kernel,    dim3(10240),  dim3(256), 0, stream, qw, wsc, part, pu, A, B);
  hipLaunchKernelGGL(gemm_kernel,     dim3(32, 32), dim3(256), 0, stream, A, B, bias, out);
}